// Round 23
// baseline (611.538 us; speedup 1.0000x reference)
//
#include <hip/hip_runtime.h>

// B=8, C=256, H=W=128, N=16384, Cq=64.
// out = gamma*linattn(conv1(x)) + BN(conv3x3(x))
// conv2_b omitted: constant per-channel shift cancels in train-mode BN.

typedef short bf16x8 __attribute__((ext_vector_type(8)));
typedef short bf16x4 __attribute__((ext_vector_type(4)));
typedef float f32x4 __attribute__((ext_vector_type(4)));

#define MFMA16(a, b, c) __builtin_amdgcn_mfma_f32_16x16x32_bf16(a, b, c, 0, 0, 0)

#define GLDS(g, s)                                                    \
  __builtin_amdgcn_global_load_lds(                                   \
      (__attribute__((address_space(1))) unsigned int*)(g),           \
      (__attribute__((address_space(3))) unsigned int*)(s), 16, 0, 0)

__device__ __forceinline__ unsigned short f2bf(float f) {
  unsigned u = __builtin_bit_cast(unsigned, f);
  u += 0x7fffu + ((u >> 16) & 1u);
  return (unsigned short)(u >> 16);
}
__device__ __forceinline__ float bf2f(unsigned short h) {
  unsigned u = ((unsigned)h) << 16;
  return __builtin_bit_cast(float, u);
}

// ---------------- compose: Wqk' = [q_w;k_w]@conv1_w (bf16), Wv' = v_w@conv1_w (f32)
__global__ __launch_bounds__(256) void compose_kernel(
    const float* conv1_w, const float* conv1_b,
    const float* q_w, const float* q_b, const float* k_w, const float* k_b,
    const float* v_w, const float* v_b,
    short* Wqk, float* bqk, float* Wv, float* bv) {
  int o = blockIdx.x;  // 0..383
  int t = threadIdx.x;
  __shared__ float row[256];
  const float* src;
  if (o < 64) src = q_w + o * 256;
  else if (o < 128) src = k_w + (o - 64) * 256;
  else src = v_w + (o - 128) * 256;
  row[t] = src[t];
  __syncthreads();
  float acc = 0.f;
  for (int k = 0; k < 256; k++) acc = fmaf(row[k], conv1_w[k * 256 + t], acc);
  if (o < 128) Wqk[o * 256 + t] = (short)f2bf(acc);
  else Wv[(o - 128) * 256 + t] = acc;
  if (t == 0) {
    float ab = 0.f;
    for (int k = 0; k < 256; k++) ab = fmaf(row[k], conv1_b[k], ab);
    if (o < 64) bqk[o] = ab + q_b[o];
    else if (o < 128) bqk[o] = ab + k_b[o - 64];
    else bv[o - 128] = ab + v_b[o - 128];
  }
}

// ---------------- conv2 weights: (O,C,3,3) f32 -> [kc][t9][oc][ic32] bf16
__global__ __launch_bounds__(256) void w2r_kernel(const float* conv2_w, short* w2r) {
  int d = blockIdx.x * 256 + threadIdx.x;  // 589824 total
  int icr = d & 31;
  int rest = d >> 5;
  int oc = rest & 255;
  int rest2 = rest >> 8;
  int t9 = rest2 % 9;
  int kcc = rest2 / 9;
  int ic = kcc * 32 + icr;
  float v = conv2_w[(oc * 256 + ic) * 9 + t9];
  w2r[d] = (short)f2bf(v);
}

// ---------------- xT[b][n][c] bf16 transpose of x, fused with xsum
__global__ __launch_bounds__(256) void xt_kernel(const float* x, short* xT, float* xsum) {
  // grid: b(8) x ctile(4: 64c) x ntile(128: 128n) = 4096
  int bid = blockIdx.x;
  int b = bid >> 9;
  int r = bid & 511;
  int ct = r >> 7, nt = r & 127;
  int c0 = ct * 64, n0 = nt * 128;
  int t = threadIdx.x;
  __shared__ short lds[64 * 128];  // [c][16 chunks of 8n], chunk-XOR-swizzled
  const float* xb = x + ((size_t)b << 22);
  #pragma unroll
  for (int j = 0; j < 4; j++) {
    int id = t + (j << 8);          // 0..1023
    int c = id >> 4, ng = id & 15;  // c 0..63, ng 0..15
    const float* src = xb + (size_t)(c0 + c) * 16384 + n0 + ng * 8;
    float4 v0 = *(const float4*)src;
    float4 v1 = *(const float4*)(src + 4);
    bf16x8 pk;
    pk[0] = (short)f2bf(v0.x); pk[1] = (short)f2bf(v0.y);
    pk[2] = (short)f2bf(v0.z); pk[3] = (short)f2bf(v0.w);
    pk[4] = (short)f2bf(v1.x); pk[5] = (short)f2bf(v1.y);
    pk[6] = (short)f2bf(v1.z); pk[7] = (short)f2bf(v1.w);
    *(bf16x8*)&lds[c * 128 + ((ng ^ (c & 15)) << 3)] = pk;
    float s = v0.x + v0.y + v0.z + v0.w + v1.x + v1.y + v1.z + v1.w;
    s += __shfl_xor(s, 1, 64); s += __shfl_xor(s, 2, 64);
    s += __shfl_xor(s, 4, 64); s += __shfl_xor(s, 8, 64);
    if ((t & 15) == 0) atomicAdd(&xsum[b * 256 + c0 + c], s);
  }
  __syncthreads();
  char* xtb = (char*)(xT + ((size_t)b << 22));
  #pragma unroll
  for (int j = 0; j < 4; j++) {
    int id = t + (j << 8);         // 0..1023
    int n = id >> 3, cg = id & 7;  // n 0..127, cg 0..7 (8 c's each)
    bf16x8 vv;
    #pragma unroll
    for (int k = 0; k < 8; k++) {
      int c = cg * 8 + k;
      vv[k] = lds[c * 128 + (((n >> 3) ^ (c & 15)) << 3) + (n & 7)];
    }
    *(bf16x8*)(xtb + (size_t)(n0 + n) * 512 + (c0 + cg * 8) * 2) = vv;
  }
}

// ---------------- QK from xT: [Q;K](128) = Wqk@x + bqk, per-position L2 norm
// writes QnT[b][n][64q] (bf16, granule-swizzled), Kn[b][q][n], kssum[b][64]
__global__ __launch_bounds__(256) void qk_kernel(
    const short* xT, const short* Wqk, const float* bqk,
    short* QnT, short* Kn, float* kssum) {
  int b = blockIdx.x >> 7;
  int n0 = (blockIdx.x & 127) << 7;  // 128 positions per block
  int t = threadIdx.x;
  int w = t >> 6, l = t & 63, lh = l >> 4, col = l & 15;
  __shared__ short lds_x[2][128 * 32];  // [px][ic32]
  __shared__ short lds_w[2][128 * 32];  // [oc][ic32]
  __shared__ float norm2[4][128];
  f32x4 acc[2][8] = {};
  const char* xb = (const char*)(xT + ((size_t)b << 22)) + (size_t)n0 * 512;
  const char* wb = (const char*)Wqk;

#define QSTAGE(buf, kc)                                                  \
  do {                                                                   \
    int koff = (kc) << 6;                                                \
    _Pragma("unroll") for (int j = 0; j < 2; j++) {                      \
      int i = t + (j << 8);                                              \
      int off = ((i >> 2) << 9) + ((i & 3) << 4) + koff;                 \
      GLDS(xb + off, &lds_x[buf][(j * 256 + w * 64) * 8]);               \
      GLDS(wb + off, &lds_w[buf][(j * 256 + w * 64) * 8]);               \
    }                                                                    \
  } while (0)

  QSTAGE(0, 0);
  __syncthreads();
  int cur = 0;
  for (int kc = 0; kc < 8; kc++) {
    if (kc < 7) QSTAGE(cur ^ 1, kc + 1);
    bf16x8 a0 = *(const bf16x8*)&lds_w[cur][(w * 32 + col) * 32 + lh * 8];
    bf16x8 a1 = *(const bf16x8*)&lds_w[cur][(w * 32 + 16 + col) * 32 + lh * 8];
    #pragma unroll
    for (int nf = 0; nf < 8; nf++) {
      bf16x8 bb = *(const bf16x8*)&lds_x[cur][(nf * 16 + col) * 32 + lh * 8];
      acc[0][nf] = MFMA16(a0, bb, acc[0][nf]);
      acc[1][nf] = MFMA16(a1, bb, acc[1][nf]);
    }
    __syncthreads();
    cur ^= 1;
  }
  // bias, then per-position sum of squares
  float bias[2][4];
  #pragma unroll
  for (int m = 0; m < 2; m++)
    #pragma unroll
    for (int r = 0; r < 4; r++) bias[m][r] = bqk[w * 32 + m * 16 + lh * 4 + r];
  #pragma unroll
  for (int m = 0; m < 2; m++)
    #pragma unroll
    for (int nf = 0; nf < 8; nf++)
      #pragma unroll
      for (int r = 0; r < 4; r++) acc[m][nf][r] += bias[m][r];
  #pragma unroll
  for (int nf = 0; nf < 8; nf++) {
    float s = 0.f;
    #pragma unroll
    for (int m = 0; m < 2; m++)
      #pragma unroll
      for (int r = 0; r < 4; r++) s += acc[m][nf][r] * acc[m][nf][r];
    s += __shfl_xor(s, 16, 64);
    s += __shfl_xor(s, 32, 64);
    if (lh == 0) norm2[w][nf * 16 + col] = s;
  }
  __syncthreads();
  if (w < 2) {
    // Q waves: write QnT[n][q] swizzled (granule g of 8 q stored at g^(n&7))
    char* qd = (char*)QnT + (((size_t)b << 14) + n0) * 128;
    #pragma unroll
    for (int nf = 0; nf < 8; nf++) {
      int px = nf * 16 + col;
      float rn = rsqrtf(norm2[0][px] + norm2[1][px]);
      #pragma unroll
      for (int m = 0; m < 2; m++) {
        bf16x4 v;
        #pragma unroll
        for (int r = 0; r < 4; r++) v[r] = (short)f2bf(acc[m][nf][r] * rn);
        int G = (w & 1) * 4 + m * 2 + (lh >> 1);
        *(bf16x4*)(qd + px * 128 + ((G ^ (px & 7)) << 4) + (lh & 1) * 8) = v;
      }
    }
  } else {
    float ks[2][4] = {};
    #pragma unroll
    for (int nf = 0; nf < 8; nf++) {
      int px = nf * 16 + col;
      float rn = rsqrtf(norm2[2][px] + norm2[3][px]);
      #pragma unroll
      for (int m = 0; m < 2; m++)
        #pragma unroll
        for (int r = 0; r < 4; r++) {
          float v = acc[m][nf][r] * rn;
          int oc = (w & 1) * 32 + m * 16 + lh * 4 + r;
          Kn[(((size_t)b * 64 + oc) << 14) + n0 + px] = (short)f2bf(v);
          ks[m][r] += v;
        }
    }
    #pragma unroll
    for (int m = 0; m < 2; m++)
      #pragma unroll
      for (int r = 0; r < 4; r++) {
        float v = ks[m][r];
        v += __shfl_xor(v, 1, 64); v += __shfl_xor(v, 2, 64);
        v += __shfl_xor(v, 4, 64); v += __shfl_xor(v, 8, 64);
        if (col == 0) {
          int oc = (w & 1) * 32 + m * 16 + lh * 4 + r;
          atomicAdd(&kssum[b * 64 + oc], v);
        }
      }
  }
}

// ---------------- Pt[b][cx][q] = sum_n Kn[q,n]*xT[n,cx]  (split-K over N, atomics)
// Sources bf16 x-values from xT; in-LDS transpose feeds lds_xc[c][n32].
__global__ __launch_bounds__(256) void p_kernel(const short* xT, const short* Kn, float* Pt) {
  int b = blockIdx.x >> 6;
  int n0 = (blockIdx.x & 63) << 8;  // 256 positions per block
  int t = threadIdx.x;
  int w = t >> 6, l = t & 63, lh = l >> 4, col = l & 15;
  __shared__ short lds_k[64 * 40];    // [q][n(32)+pad]
  __shared__ short lds_t[32 * 264];   // xT chunk [nn][c], granule-XOR swizzled
  __shared__ short lds_xc[256 * 40];  // [cx][n(32)+pad]
  f32x4 acc[4][4] = {};
  const short* xb = xT + ((size_t)b << 22);
  const short* kb = Kn + ((size_t)b << 20);
  for (int ch = 0; ch < 8; ch++) {
    int nb = n0 + (ch << 5);
    {
      int q = t >> 2, g = t & 3;
      *(bf16x8*)&lds_k[q * 40 + g * 8] =
          *(const bf16x8*)&kb[((size_t)q << 14) + nb + g * 8];
    }
    // stage xT chunk (32 n x 256 c), coalesced; row-granule XOR swizzle
    #pragma unroll
    for (int j = 0; j < 4; j++) {
      int id = t + (j << 8);          // 0..1023
      int nn = id >> 5, cg = id & 31; // nn 0..31, cg 0..31 (8 c each)
      bf16x8 v = *(const bf16x8*)&xb[(size_t)(nb + nn) * 256 + cg * 8];
      *(bf16x8*)&lds_t[nn * 264 + ((cg ^ nn) << 3)] = v;
    }
    __syncthreads();
    // transpose into [c][n32]
    #pragma unroll
    for (int j = 0; j < 4; j++) {
      int id = t + (j << 8);          // 0..1023
      int c = id >> 2, ng = id & 3;   // c 0..255, ng 0..3 (8 n each)
      int cg = c >> 3, e = c & 7;
      bf16x8 pk;
      #pragma unroll
      for (int k = 0; k < 8; k++) {
        int nn = ng * 8 + k;
        pk[k] = lds_t[nn * 264 + ((cg ^ nn) << 3) + e];
      }
      *(bf16x8*)&lds_xc[c * 40 + ng * 8] = pk;
    }
    __syncthreads();
    bf16x8 a[4];
    #pragma unroll
    for (int m = 0; m < 4; m++) a[m] = *(bf16x8*)&lds_k[(m * 16 + col) * 40 + lh * 8];
    #pragma unroll
    for (int nf = 0; nf < 4; nf++) {
      bf16x8 bb = *(bf16x8*)&lds_xc[(w * 64 + nf * 16 + col) * 40 + lh * 8];
      #pragma unroll
      for (int m = 0; m < 4; m++) acc[m][nf] = MFMA16(a[m], bb, acc[m][nf]);
    }
    __syncthreads();
  }
  #pragma unroll
  for (int m = 0; m < 4; m++)
    #pragma unroll
    for (int nf = 0; nf < 4; nf++)
      #pragma unroll
      for (int r = 0; r < 4; r++) {
        int q = m * 16 + lh * 4 + r;
        int c = w * 64 + nf * 16 + col;
        atomicAdd(&Pt[(((size_t)b << 8) + c) * 64 + q], acc[m][nf][r]);
      }
}

// ---------------- conv3x3 implicit GEMM from xT + BN partial stats
// Depth-3 staging with counted vmcnt (T3+T4) + register double-buffered
// A-fragments (r19 structure). T1 XCD swizzle: bid = (blockIdx&7)*256 +
// blockIdx>>3 (bijective, 2048=8*256) puts all 4 ocb-siblings of a tile on
// the same XCD so the shared halo is fetched once per L2 instead of 4x.
// BF16OUT=1: write c2 bf16 to c2b [n][c] (packed bf16x4 per thread).
template <int BF16OUT>
__global__ __launch_bounds__(256, 2) void conv_kernel(
    const short* xT, const short* w2r, float* out, short* c2b,
    float* bnsum, float* bnsumsq, const char* zeropage) {
  int bid = ((blockIdx.x & 7) << 8) | (blockIdx.x >> 3);  // T1 XCD swizzle
  int b = bid >> 8;
  int r255 = bid & 255;
  int tile = r255 >> 2, ocb = r255 & 3;  // ocb innermost: halo L2 reuse
  int ty = tile >> 3, tx = tile & 7;
  int oc0 = ocb * 64, oy0 = ty * 16, ox0 = tx * 16;
  int t = threadIdx.x;
  int w = t >> 6, l = t & 63, lh = l >> 4, col = l & 15;
  __shared__ short lds_in[3][1536 * 8];  // 3 x 24KB halo buffers
  int ocl = (w >> 1) * 32;
  int pyb = (w & 1) * 8;
  const char* xb = (const char*)(xT + ((size_t)b << 22));
  const char* gp[6];
  #pragma unroll
  for (int j = 0; j < 6; j++) {
    int i = t + (j << 8);
    int px = i >> 2, g = i & 3;
    int iy = px / 18, ix = px - iy * 18;
    int gy = oy0 - 1 + iy, gx = ox0 - 1 + ix;
    bool valid = (px < 324) && ((unsigned)gy < 128u) && ((unsigned)gx < 128u);
    gp[j] = valid ? xb + (((size_t)(gy << 7) + gx) << 9) + (g << 4) : zeropage;
  }

#define CSTAGE(dst, kc)                                                  \
  do {                                                                   \
    int koff = (kc) << 6;                                                \
    _Pragma("unroll") for (int j = 0; j < 6; j++) {                      \
      GLDS(gp[j] + koff, (dst) + (j * 256 + w * 64) * 8);                \
    }                                                                    \
  } while (0)

  // [kc][t9][oc][ic32]: wave base = (oc0+ocl+col)*32 + lh*8
  const short* wp = w2r + (size_t)(oc0 + ocl + col) * 32 + lh * 8;
  f32x4 acc[2][8] = {};
  bf16x8 Aa0[9], Aa1[9], Ab0[9], Ab1[9];
  CSTAGE(&lds_in[0][0], 0);
  CSTAGE(&lds_in[1][0], 1);
  #pragma unroll
  for (int t9 = 0; t9 < 9; t9++) {
    Aa0[t9] = *(const bf16x8*)(wp + t9 * 8192);
    Aa1[t9] = *(const bf16x8*)(wp + t9 * 8192 + 512);
  }
  asm volatile("s_waitcnt vmcnt(24)" ::: "memory");
  __builtin_amdgcn_s_barrier();
  __builtin_amdgcn_sched_barrier(0);

#define CONVSTEP(kc, Au0, Au1, Ap0, Ap1)                                   \
  do {                                                                     \
    short* cbuf = &lds_in[0][0] + ((kc) % 3) * 12288;                      \
    if ((kc) < 7) {                                                        \
      const short* wk = wp + ((kc) + 1) * 73728;                           \
      _Pragma("unroll") for (int t9 = 0; t9 < 9; t9++) {                   \
        Ap0[t9] = *(const bf16x8*)(wk + t9 * 8192);                        \
        Ap1[t9] = *(const bf16x8*)(wk + t9 * 8192 + 512);                  \
      }                                                                    \
    }                                                                      \
    if ((kc) < 6) CSTAGE(&lds_in[0][0] + (((kc) + 2) % 3) * 12288, (kc) + 2); \
    _Pragma("unroll") for (int rr = 0; rr < 10; rr++) {                    \
      bf16x8 fb[3];                                                        \
      _Pragma("unroll") for (int kw = 0; kw < 3; kw++)                     \
        fb[kw] = *(const bf16x8*)                                          \
            &cbuf[((pyb + rr) * 18 + col + kw) * 32 + lh * 8];             \
      _Pragma("unroll") for (int kw = 0; kw < 3; kw++) {                   \
        _Pragma("unroll") for (int kh = 0; kh < 3; kh++) {                 \
          int nf = rr - kh;                                                \
          if (nf >= 0 && nf < 8) {                                         \
            acc[0][nf] = MFMA16(Au0[kh * 3 + kw], fb[kw], acc[0][nf]);     \
            acc[1][nf] = MFMA16(Au1[kh * 3 + kw], fb[kw], acc[1][nf]);     \
          }                                                                \
        }                                                                  \
      }                                                                    \
    }                                                                      \
    if ((kc) < 6) {                                                        \
      asm volatile("s_waitcnt vmcnt(24)" ::: "memory");                    \
      __builtin_amdgcn_s_barrier();                                        \
      __builtin_amdgcn_sched_barrier(0);                                   \
    } else if ((kc) == 6) {                                                \
      asm volatile("s_waitcnt vmcnt(18)" ::: "memory");                    \
      __builtin_amdgcn_s_barrier();                                        \
      __builtin_amdgcn_sched_barrier(0);                                   \
    }                                                                      \
  } while (0)

  CONVSTEP(0, Aa0, Aa1, Ab0, Ab1);
  CONVSTEP(1, Ab0, Ab1, Aa0, Aa1);
  CONVSTEP(2, Aa0, Aa1, Ab0, Ab1);
  CONVSTEP(3, Ab0, Ab1, Aa0, Aa1);
  CONVSTEP(4, Aa0, Aa1, Ab0, Ab1);
  CONVSTEP(5, Ab0, Ab1, Aa0, Aa1);
  CONVSTEP(6, Aa0, Aa1, Ab0, Ab1);
  CONVSTEP(7, Ab0, Ab1, Aa0, Aa1);

  float* ob = out + ((size_t)b << 22);
  short* cb = c2b + ((size_t)b << 22);  // [n][c] layout when BF16OUT
  float s1[2][4] = {}, s2[2][4] = {};
  #pragma unroll
  for (int m = 0; m < 2; m++)
    #pragma unroll
    for (int nf = 0; nf < 8; nf++) {
      int oy = oy0 + pyb + nf;
      if (BF16OUT) {
        bf16x4 pv;
        #pragma unroll
        for (int r = 0; r < 4; r++) {
          float v = acc[m][nf][r];
          pv[r] = (short)f2bf(v);
          s1[m][r] += v;
          s2[m][r] += v * v;
        }
        int n = (oy << 7) + ox0 + col;
        int c = oc0 + ocl + m * 16 + lh * 4;
        *(bf16x4*)&cb[(size_t)n * 256 + c] = pv;
      } else {
        #pragma unroll
        for (int r = 0; r < 4; r++) {
          float v = acc[m][nf][r];
          int oc = oc0 + ocl + m * 16 + lh * 4 + r;
          ob[((size_t)oc << 14) + (oy << 7) + ox0 + col] = v;
          s1[m][r] += v;
          s2[m][r] += v * v;
        }
      }
    }
  #pragma unroll
  for (int m = 0; m < 2; m++)
    #pragma unroll
    for (int r = 0; r < 4; r++) {
      float a1v = s1[m][r], a2v = s2[m][r];
      a1v += __shfl_xor(a1v, 1, 64); a1v += __shfl_xor(a1v, 2, 64);
      a1v += __shfl_xor(a1v, 4, 64); a1v += __shfl_xor(a1v, 8, 64);
      a2v += __shfl_xor(a2v, 1, 64); a2v += __shfl_xor(a2v, 2, 64);
      a2v += __shfl_xor(a2v, 4, 64); a2v += __shfl_xor(a2v, 8, 64);
      if (col == 0) {
        int oc = oc0 + ocl + m * 16 + lh * 4 + r;
        atomicAdd(&bnsum[oc], a1v);
        atomicAdd(&bnsumsq[oc], a2v);
      }
    }
}

// ---------------- Mtb (bf16, swizzled) rows 0..255: Wv'@Pt + bv'*kssum
//                  rows 256..271: den tile (row 256 = kssum+eps, rest 0)
// Block 0 additionally computes BN scale/shift (bnfin folded in; conv has
// completed in stream order so bnsum/bnsumsq are final).
__global__ __launch_bounds__(256) void mt_kernel(
    const float* Wv, const float* bv, const float* Pt, const float* xsum,
    const float* kssum, short* Mtb, float* vsum,
    const float* bnsum, const float* bnsumsq,
    const float* bn_w, const float* bn_b, float* bnscale, float* bnshift) {
  int b = blockIdx.x >> 2, qg = blockIdx.x & 3;
  int c = threadIdx.x;
  if (blockIdx.x == 0) {
    const float inv = 1.f / 131072.f;
    float mean = bnsum[c] * inv;
    float var = bnsumsq[c] * inv - mean * mean;
    float sc = bn_w[c] * rsqrtf(var + 1e-5f);
    bnscale[c] = sc;
    bnshift[c] = bn_b[c] - mean * sc;
  }
  const float* wrow = Wv + c * 256;
  const float* pb = Pt + ((size_t)b << 14);
  const float* xs = xsum + b * 256;
  float acc[16] = {};
  float vs = 0.f;
  for (int k = 0; k < 256; k++) {
    float wv = wrow[k];
    const float* pr = pb + k * 64 + qg * 16;
    #pragma unroll
    for (int j = 0; j < 16; j++) acc[j] = fmaf(wv, pr[j], acc[j]);
    if (qg == 0) vs = fmaf(wv, xs[k], vs);
  }
  float bvc = bv[c];
  char* mb = (char*)Mtb + (size_t)b * 34816;
  #pragma unroll
  for (int h = 0; h < 2; h++) {
    bf16x8 v;
    #pragma unroll
    for (int j = 0; j < 8; j++) {
      int q = qg * 16 + h * 8 + j;
      v[j] = (short)f2bf(acc[h * 8 + j] + bvc * kssum[b * 64 + q]);
    }
    int G = qg * 2 + h;
    *(bf16x8*)(mb + c * 128 + ((G ^ (c & 7)) << 4)) = v;
  }
  if (qg == 0) vsum[b * 256 + c] = vs + 16384.f * bvc;
  if (c < 16) {
    int row = 256 + c;
    #pragma unroll
    for (int h = 0; h < 2; h++) {
      bf16x8 v;
      #pragma unroll
      for (int j = 0; j < 8; j++)
        v[j] = (c == 0) ? (short)f2bf(kssum[b * 64 + qg * 16 + h * 8 + j] + 1e-6f)
                        : (short)0;
      int G = qg * 2 + h;
      *(bf16x8*)(mb + row * 128 + ((G ^ (row & 7)) << 4)) = v;
    }
  }
}

// ---------------- final: out = gamma*tailor*(vsum + Qn^T@M) + BN(conv raw)
// MFMA: D[c][n] = Mtb[c][q] x QnT[n][q]; den via extra A-tile rows 256..271
// BF16C2=1: conv result read from c2b [n][c] bf16 (packed bf16x4 per m).
template <int BF16C2>
__global__ __launch_bounds__(256, 3) void final_kernel(
    const short* Mtb, const short* QnT, const short* c2b, const float* vsum,
    const float* bnscale, const float* bnshift, const float* gamma, float* out) {
  int b = blockIdx.x >> 7;
  int n0 = (blockIdx.x & 127) << 7;  // 128 n per block
  int t = threadIdx.x;
  int w = t >> 6, l = t & 63, lh = l >> 4, col = l & 15;
  __shared__ short mtb_lds[272 * 64];  // [row][64q], granule-swizzled
  __shared__ short qnt_lds[128 * 64];  // [n][64q], granule-swizzled
  const char* mb = (const char*)Mtb + (size_t)b * 34816;
  const char* qb = (const char*)QnT + (((size_t)b << 14) + n0) * 128;
  #pragma unroll
  for (int j = 0; j < 8; j++) {
    int i = t + (j << 8);
    GLDS(mb + i * 16, &mtb_lds[(j * 256 + w * 64) * 8]);
  }
  if (t < 128) {
    GLDS(mb + (t + 2048) * 16, &mtb_lds[(2048 + w * 64) * 8]);
  }
  #pragma unroll
  for (int j = 0; j < 4; j++) {
    int i = t + (j << 8);
    GLDS(qb + i * 16, &qnt_lds[(j * 256 + w * 64) * 8]);
  }
  float g = gamma[0];
  __syncthreads();
  #pragma unroll
  for (int nt = 0; nt < 2; nt++) {
    int nl = w * 32 + nt * 16 + col;  // local n row
    bf16x8 bfrag[2];
    #pragma unroll
    for (int kk = 0; kk < 2; kk++) {
      int gsl = (kk * 4 + lh) ^ (nl & 7);
      bfrag[kk] = *(const bf16x8*)&qnt_lds[nl * 64 + gsl * 8];
    }
    // den tile (A rows 256..271, row 256 = ks+eps); den for col n sits in
    // lane col (lh==0, reg 0) -> broadcast via shfl, no LDS round-trip
    f32x4 dacc = {};
    #pragma unroll
    for (int kk = 0; kk < 2; kk++) {
      int cr = 256 + col;
      int gsl = (kk * 4 + lh) ^ (cr & 7);
      bf16x8 afrag = *(const bf16x8*)&mtb_lds[cr * 64 + gsl * 8];
      dacc = MFMA16(afrag, bfrag[kk], dacc);
    }
    float den = __shfl(dacc[0], col, 64);
    float taiv = g / (16384.f + den);
    size_t base = ((size_t)b << 22) + n0 + w * 32 + nt * 16 + col;
    float* ob = out + base;
    // c2b [n][c]: row base for this thread's n
    const short* cb = c2b + ((size_t)b << 22) +
                      (size_t)(n0 + w * 32 + nt * 16 + col) * 256;
    const float* vsb = vsum + b * 256;
    #pragma unroll
    for (int m = 0; m < 16; m++) {
      f32x4 acc = {};
      #pragma unroll
      for (int kk = 0; kk < 2; kk++) {
        int cr = m * 16 + col;
        int gsl = (kk * 4 + lh) ^ (cr & 7);
        bf16x8 afrag = *(const bf16x8*)&mtb_lds[cr * 64 + gsl * 8];
        acc = MFMA16(afrag, bfrag[kk], acc);
      }
      int c0 = m * 16 + lh * 4;
      bf16x4 cv = {};
      if (BF16C2) cv = *(const bf16x4*)&cb[c0];
      f32x4 vsv = *(const f32x4*)&vsb[c0];
      f32x4 scv = *(const f32x4*)&bnscale[c0];
      f32x4 shv = *(const f32x4*)&bnshift[c0];
      #pragma unroll
      for (int r = 0; r < 4; r++) {
        float att = vsv[r] + acc[r];
        float c2 = BF16C2 ? bf2f((unsigned short)cv[r])
                          : ob[(size_t)(c0 + r) << 14];
        ob[(size_t)(c0 + r) << 14] = fmaf(taiv, att, fmaf(c2, scv[r], shv[r]));
      }
    }
  }
}

extern "C" void kernel_launch(void* const* d_in, const int* in_sizes, int n_in,
                              void* d_out, int out_size, void* d_ws, size_t ws_size,
                              hipStream_t stream) {
  const float* x = (const float*)d_in[0];
  const float* conv1_w = (const float*)d_in[1];
  const float* conv1_b = (const float*)d_in[2];
  const float* q_w = (const float*)d_in[3];
  const float* q_b = (const float*)d_in[4];
  const float* k_w = (const float*)d_in[5];
  const float* k_b = (const float*)d_in[6];
  const float* v_w = (const float*)d_in[7];
  const float* v_b = (const float*)d_in[8];
  const float* gamma = (const float*)d_in[9];
  const float* conv2_w = (const float*)d_in[10];
  // d_in[11] = conv2_b: unused, cancels exactly in train-mode BN
  const float* bn_w = (const float*)d_in[12];
  const float* bn_b = (const float*)d_in[13];

  char* ws = (char*)d_ws;
  char* zeropage = ws + 0;                   // 1024 (zeroed)
  float* kssum   = (float*)(ws + 1024);      // 8*64 (zeroed)
  float* bnsum   = (float*)(ws + 3072);      // 256 (zeroed)
  float* bnsumsq = (float*)(ws + 4096);      // 256 (zeroed)
  float* xsum    = (float*)(ws + 5120);      // 8*256 (zeroed)
  float* Pt      = (float*)(ws + 13312);     // 8*256*64 (zeroed)
  short* Wqk     = (short*)(ws + 537600);    // 128*256 bf16
  float* bqk     = (float*)(ws + 603136);    // 128
  float* Wv      = (float*)(ws + 603648);    // 256*256
  float* bv      = (float*)(ws + 865792);    // 256
  short* w2r     = (short*)(ws + 866816);    // [kc][t9][oc][ic32] bf16
  short* Mtb     = (short*)(ws + 2046464);   // 8*272*64 bf16 swizzled
  float* vsum    = (float*)(ws + 2324992);   // 8*256
  float* bnscale = (float*)(ws + 2333184);   // 256
  float* bnshift = (float*)(ws + 2334208);   // 256
  short* xT      = (short*)(ws + 2336768);   // 8*16384*256 bf16 (64 MB)
  short* QnT     = (short*)(ws + 69445632);  // 8*16384*64 bf16 swizzled
  short* Kn      = (short*)(ws + 86222848);  // 8*64*16384 bf16
  short* c2b     = (short*)(ws + 103000064); // 8*16384*256 bf16 [n][c] (64 MB)
  const size_t NEED_BF16 = 103000064ULL + 67108864ULL;  // 170,108,928

  float* out = (float*)d_out;
  bool use_bf16_c2 = (ws_size >= NEED_BF16);

  hipMemsetAsync(ws, 0, 537600, stream);  // zeropage..Pt
  compose_kernel<<<384, 256, 0, stream>>>(conv1_w, conv1_b, q_w, q_b, k_w, k_b,
                                          v_w, v_b, Wqk, bqk, Wv, bv);
  w2r_kernel<<<2304, 256, 0, stream>>>(conv2_w, w2r);
  xt_kernel<<<4096, 256, 0, stream>>>(x, xT, xsum);
  qk_kernel<<<1024, 256, 0, stream>>>(xT, Wqk, bqk, QnT, Kn, kssum);
  p_kernel<<<512, 256, 0, stream>>>(xT, Kn, Pt);
  if (use_bf16_c2)
    conv_kernel<1><<<2048, 256, 0, stream>>>(xT, w2r, out, c2b, bnsum, bnsumsq,
                                             zeropage);
  else
    conv_kernel<0><<<2048, 256, 0, stream>>>(xT, w2r, out, c2b, bnsum, bnsumsq,
                                             zeropage);
  mt_kernel<<<32, 256, 0, stream>>>(Wv, bv, Pt, xsum, kssum, Mtb, vsum,
                                    bnsum, bnsumsq, bn_w, bn_b, bnscale, bnshift);
  if (use_bf16_c2)
    final_kernel<1><<<1024, 256, 0, stream>>>(Mtb, QnT, c2b, vsum, bnscale,
                                              bnshift, gamma, out);
  else
    final_kernel<0><<<1024, 256, 0, stream>>>(Mtb, QnT, c2b, vsum, bnscale,
                                              bnshift, gamma, out);
}

// Round 24
// 543.958 us; speedup vs baseline: 1.1242x; 1.1242x over previous
//
#include <hip/hip_runtime.h>

// B=8, C=256, H=W=128, N=16384, Cq=64.
// out = gamma*linattn(conv1(x)) + BN(conv3x3(x))
// conv2_b omitted: constant per-channel shift cancels in train-mode BN.

typedef short bf16x8 __attribute__((ext_vector_type(8)));
typedef short bf16x4 __attribute__((ext_vector_type(4)));
typedef float f32x4 __attribute__((ext_vector_type(4)));

#define MFMA16(a, b, c) __builtin_amdgcn_mfma_f32_16x16x32_bf16(a, b, c, 0, 0, 0)

#define GLDS(g, s)                                                    \
  __builtin_amdgcn_global_load_lds(                                   \
      (__attribute__((address_space(1))) unsigned int*)(g),           \
      (__attribute__((address_space(3))) unsigned int*)(s), 16, 0, 0)

__device__ __forceinline__ unsigned short f2bf(float f) {
  unsigned u = __builtin_bit_cast(unsigned, f);
  u += 0x7fffu + ((u >> 16) & 1u);
  return (unsigned short)(u >> 16);
}
__device__ __forceinline__ float bf2f(unsigned short h) {
  unsigned u = ((unsigned)h) << 16;
  return __builtin_bit_cast(float, u);
}

// ---------------- compose: Wqk' = [q_w;k_w]@conv1_w (bf16), Wv' = v_w@conv1_w (f32)
__global__ __launch_bounds__(256) void compose_kernel(
    const float* conv1_w, const float* conv1_b,
    const float* q_w, const float* q_b, const float* k_w, const float* k_b,
    const float* v_w, const float* v_b,
    short* Wqk, float* bqk, float* Wv, float* bv) {
  int o = blockIdx.x;  // 0..383
  int t = threadIdx.x;
  __shared__ float row[256];
  const float* src;
  if (o < 64) src = q_w + o * 256;
  else if (o < 128) src = k_w + (o - 64) * 256;
  else src = v_w + (o - 128) * 256;
  row[t] = src[t];
  __syncthreads();
  float acc = 0.f;
  for (int k = 0; k < 256; k++) acc = fmaf(row[k], conv1_w[k * 256 + t], acc);
  if (o < 128) Wqk[o * 256 + t] = (short)f2bf(acc);
  else Wv[(o - 128) * 256 + t] = acc;
  if (t == 0) {
    float ab = 0.f;
    for (int k = 0; k < 256; k++) ab = fmaf(row[k], conv1_b[k], ab);
    if (o < 64) bqk[o] = ab + q_b[o];
    else if (o < 128) bqk[o] = ab + k_b[o - 64];
    else bv[o - 128] = ab + v_b[o - 128];
  }
}

// ---------------- conv2 weights: (O,C,3,3) f32 -> [kc][t9][oc][ic32] bf16
__global__ __launch_bounds__(256) void w2r_kernel(const float* conv2_w, short* w2r) {
  int d = blockIdx.x * 256 + threadIdx.x;  // 589824 total
  int icr = d & 31;
  int rest = d >> 5;
  int oc = rest & 255;
  int rest2 = rest >> 8;
  int t9 = rest2 % 9;
  int kcc = rest2 / 9;
  int ic = kcc * 32 + icr;
  float v = conv2_w[(oc * 256 + ic) * 9 + t9];
  w2r[d] = (short)f2bf(v);
}

// ---------------- xT[b][n][c] bf16 transpose of x, fused with xsum
__global__ __launch_bounds__(256) void xt_kernel(const float* x, short* xT, float* xsum) {
  // grid: b(8) x ctile(4: 64c) x ntile(128: 128n) = 4096
  int bid = blockIdx.x;
  int b = bid >> 9;
  int r = bid & 511;
  int ct = r >> 7, nt = r & 127;
  int c0 = ct * 64, n0 = nt * 128;
  int t = threadIdx.x;
  __shared__ short lds[64 * 128];  // [c][16 chunks of 8n], chunk-XOR-swizzled
  const float* xb = x + ((size_t)b << 22);
  #pragma unroll
  for (int j = 0; j < 4; j++) {
    int id = t + (j << 8);          // 0..1023
    int c = id >> 4, ng = id & 15;  // c 0..63, ng 0..15
    const float* src = xb + (size_t)(c0 + c) * 16384 + n0 + ng * 8;
    float4 v0 = *(const float4*)src;
    float4 v1 = *(const float4*)(src + 4);
    bf16x8 pk;
    pk[0] = (short)f2bf(v0.x); pk[1] = (short)f2bf(v0.y);
    pk[2] = (short)f2bf(v0.z); pk[3] = (short)f2bf(v0.w);
    pk[4] = (short)f2bf(v1.x); pk[5] = (short)f2bf(v1.y);
    pk[6] = (short)f2bf(v1.z); pk[7] = (short)f2bf(v1.w);
    *(bf16x8*)&lds[c * 128 + ((ng ^ (c & 15)) << 3)] = pk;
    float s = v0.x + v0.y + v0.z + v0.w + v1.x + v1.y + v1.z + v1.w;
    s += __shfl_xor(s, 1, 64); s += __shfl_xor(s, 2, 64);
    s += __shfl_xor(s, 4, 64); s += __shfl_xor(s, 8, 64);
    if ((t & 15) == 0) atomicAdd(&xsum[b * 256 + c0 + c], s);
  }
  __syncthreads();
  char* xtb = (char*)(xT + ((size_t)b << 22));
  #pragma unroll
  for (int j = 0; j < 4; j++) {
    int id = t + (j << 8);         // 0..1023
    int n = id >> 3, cg = id & 7;  // n 0..127, cg 0..7 (8 c's each)
    bf16x8 vv;
    #pragma unroll
    for (int k = 0; k < 8; k++) {
      int c = cg * 8 + k;
      vv[k] = lds[c * 128 + (((n >> 3) ^ (c & 15)) << 3) + (n & 7)];
    }
    *(bf16x8*)(xtb + (size_t)(n0 + n) * 512 + (c0 + cg * 8) * 2) = vv;
  }
}

// ---------------- QK from xT: [Q;K](128) = Wqk@x + bqk, per-position L2 norm
// writes QnT[b][n][64q] (bf16, granule-swizzled), Kn[b][q][n], kssum[b][64]
__global__ __launch_bounds__(256) void qk_kernel(
    const short* xT, const short* Wqk, const float* bqk,
    short* QnT, short* Kn, float* kssum) {
  int b = blockIdx.x >> 7;
  int n0 = (blockIdx.x & 127) << 7;  // 128 positions per block
  int t = threadIdx.x;
  int w = t >> 6, l = t & 63, lh = l >> 4, col = l & 15;
  __shared__ short lds_x[2][128 * 32];  // [px][ic32]
  __shared__ short lds_w[2][128 * 32];  // [oc][ic32]
  __shared__ float norm2[4][128];
  f32x4 acc[2][8] = {};
  const char* xb = (const char*)(xT + ((size_t)b << 22)) + (size_t)n0 * 512;
  const char* wb = (const char*)Wqk;

#define QSTAGE(buf, kc)                                                  \
  do {                                                                   \
    int koff = (kc) << 6;                                                \
    _Pragma("unroll") for (int j = 0; j < 2; j++) {                      \
      int i = t + (j << 8);                                              \
      int off = ((i >> 2) << 9) + ((i & 3) << 4) + koff;                 \
      GLDS(xb + off, &lds_x[buf][(j * 256 + w * 64) * 8]);               \
      GLDS(wb + off, &lds_w[buf][(j * 256 + w * 64) * 8]);               \
    }                                                                    \
  } while (0)

  QSTAGE(0, 0);
  __syncthreads();
  int cur = 0;
  for (int kc = 0; kc < 8; kc++) {
    if (kc < 7) QSTAGE(cur ^ 1, kc + 1);
    bf16x8 a0 = *(const bf16x8*)&lds_w[cur][(w * 32 + col) * 32 + lh * 8];
    bf16x8 a1 = *(const bf16x8*)&lds_w[cur][(w * 32 + 16 + col) * 32 + lh * 8];
    #pragma unroll
    for (int nf = 0; nf < 8; nf++) {
      bf16x8 bb = *(const bf16x8*)&lds_x[cur][(nf * 16 + col) * 32 + lh * 8];
      acc[0][nf] = MFMA16(a0, bb, acc[0][nf]);
      acc[1][nf] = MFMA16(a1, bb, acc[1][nf]);
    }
    __syncthreads();
    cur ^= 1;
  }
  // bias, then per-position sum of squares
  float bias[2][4];
  #pragma unroll
  for (int m = 0; m < 2; m++)
    #pragma unroll
    for (int r = 0; r < 4; r++) bias[m][r] = bqk[w * 32 + m * 16 + lh * 4 + r];
  #pragma unroll
  for (int m = 0; m < 2; m++)
    #pragma unroll
    for (int nf = 0; nf < 8; nf++)
      #pragma unroll
      for (int r = 0; r < 4; r++) acc[m][nf][r] += bias[m][r];
  #pragma unroll
  for (int nf = 0; nf < 8; nf++) {
    float s = 0.f;
    #pragma unroll
    for (int m = 0; m < 2; m++)
      #pragma unroll
      for (int r = 0; r < 4; r++) s += acc[m][nf][r] * acc[m][nf][r];
    s += __shfl_xor(s, 16, 64);
    s += __shfl_xor(s, 32, 64);
    if (lh == 0) norm2[w][nf * 16 + col] = s;
  }
  __syncthreads();
  if (w < 2) {
    // Q waves: write QnT[n][q] swizzled (granule g of 8 q stored at g^(n&7))
    char* qd = (char*)QnT + (((size_t)b << 14) + n0) * 128;
    #pragma unroll
    for (int nf = 0; nf < 8; nf++) {
      int px = nf * 16 + col;
      float rn = rsqrtf(norm2[0][px] + norm2[1][px]);
      #pragma unroll
      for (int m = 0; m < 2; m++) {
        bf16x4 v;
        #pragma unroll
        for (int r = 0; r < 4; r++) v[r] = (short)f2bf(acc[m][nf][r] * rn);
        int G = (w & 1) * 4 + m * 2 + (lh >> 1);
        *(bf16x4*)(qd + px * 128 + ((G ^ (px & 7)) << 4) + (lh & 1) * 8) = v;
      }
    }
  } else {
    float ks[2][4] = {};
    #pragma unroll
    for (int nf = 0; nf < 8; nf++) {
      int px = nf * 16 + col;
      float rn = rsqrtf(norm2[2][px] + norm2[3][px]);
      #pragma unroll
      for (int m = 0; m < 2; m++)
        #pragma unroll
        for (int r = 0; r < 4; r++) {
          float v = acc[m][nf][r] * rn;
          int oc = (w & 1) * 32 + m * 16 + lh * 4 + r;
          Kn[(((size_t)b * 64 + oc) << 14) + n0 + px] = (short)f2bf(v);
          ks[m][r] += v;
        }
    }
    #pragma unroll
    for (int m = 0; m < 2; m++)
      #pragma unroll
      for (int r = 0; r < 4; r++) {
        float v = ks[m][r];
        v += __shfl_xor(v, 1, 64); v += __shfl_xor(v, 2, 64);
        v += __shfl_xor(v, 4, 64); v += __shfl_xor(v, 8, 64);
        if (col == 0) {
          int oc = (w & 1) * 32 + m * 16 + lh * 4 + r;
          atomicAdd(&kssum[b * 64 + oc], v);
        }
      }
  }
}

// ---------------- Pt[b][cx][q] = sum_n Kn[q,n]*xT[n,cx]  (split-K over N, atomics)
// Sources bf16 x-values from xT; in-LDS transpose feeds lds_xc[c][n32].
__global__ __launch_bounds__(256) void p_kernel(const short* xT, const short* Kn, float* Pt) {
  int b = blockIdx.x >> 6;
  int n0 = (blockIdx.x & 63) << 8;  // 256 positions per block
  int t = threadIdx.x;
  int w = t >> 6, l = t & 63, lh = l >> 4, col = l & 15;
  __shared__ short lds_k[64 * 40];    // [q][n(32)+pad]
  __shared__ short lds_t[32 * 264];   // xT chunk [nn][c], granule-XOR swizzled
  __shared__ short lds_xc[256 * 40];  // [cx][n(32)+pad]
  f32x4 acc[4][4] = {};
  const short* xb = xT + ((size_t)b << 22);
  const short* kb = Kn + ((size_t)b << 20);
  for (int ch = 0; ch < 8; ch++) {
    int nb = n0 + (ch << 5);
    {
      int q = t >> 2, g = t & 3;
      *(bf16x8*)&lds_k[q * 40 + g * 8] =
          *(const bf16x8*)&kb[((size_t)q << 14) + nb + g * 8];
    }
    // stage xT chunk (32 n x 256 c), coalesced; row-granule XOR swizzle
    #pragma unroll
    for (int j = 0; j < 4; j++) {
      int id = t + (j << 8);          // 0..1023
      int nn = id >> 5, cg = id & 31; // nn 0..31, cg 0..31 (8 c each)
      bf16x8 v = *(const bf16x8*)&xb[(size_t)(nb + nn) * 256 + cg * 8];
      *(bf16x8*)&lds_t[nn * 264 + ((cg ^ nn) << 3)] = v;
    }
    __syncthreads();
    // transpose into [c][n32]
    #pragma unroll
    for (int j = 0; j < 4; j++) {
      int id = t + (j << 8);          // 0..1023
      int c = id >> 2, ng = id & 3;   // c 0..255, ng 0..3 (8 n each)
      int cg = c >> 3, e = c & 7;
      bf16x8 pk;
      #pragma unroll
      for (int k = 0; k < 8; k++) {
        int nn = ng * 8 + k;
        pk[k] = lds_t[nn * 264 + ((cg ^ nn) << 3) + e];
      }
      *(bf16x8*)&lds_xc[c * 40 + ng * 8] = pk;
    }
    __syncthreads();
    bf16x8 a[4];
    #pragma unroll
    for (int m = 0; m < 4; m++) a[m] = *(bf16x8*)&lds_k[(m * 16 + col) * 40 + lh * 8];
    #pragma unroll
    for (int nf = 0; nf < 4; nf++) {
      bf16x8 bb = *(bf16x8*)&lds_xc[(w * 64 + nf * 16 + col) * 40 + lh * 8];
      #pragma unroll
      for (int m = 0; m < 4; m++) acc[m][nf] = MFMA16(a[m], bb, acc[m][nf]);
    }
    __syncthreads();
  }
  #pragma unroll
  for (int m = 0; m < 4; m++)
    #pragma unroll
    for (int nf = 0; nf < 4; nf++)
      #pragma unroll
      for (int r = 0; r < 4; r++) {
        int q = m * 16 + lh * 4 + r;
        int c = w * 64 + nf * 16 + col;
        atomicAdd(&Pt[(((size_t)b << 8) + c) * 64 + q], acc[m][nf][r]);
      }
}

// ---------------- conv3x3 implicit GEMM from xT + BN partial stats
// Depth-3 staging with counted vmcnt (T3+T4) + register double-buffered
// A-fragments (r19 structure). T1 XCD swizzle: bid = (blockIdx&7)*256 +
// blockIdx>>3 (bijective, 2048=8*256) puts all 4 ocb-siblings of a tile on
// the same XCD so the shared halo is fetched once per L2 instead of 4x
// (counter-verified r23: FETCH 150->47 MB).
// BF16OUT=1: write c2 bf16 to c2b [n][c] (packed bf16x4 per thread).
template <int BF16OUT>
__global__ __launch_bounds__(256, 2) void conv_kernel(
    const short* xT, const short* w2r, float* out, short* c2b,
    float* bnsum, float* bnsumsq, const char* zeropage) {
  int bid = ((blockIdx.x & 7) << 8) | (blockIdx.x >> 3);  // T1 XCD swizzle
  int b = bid >> 8;
  int r255 = bid & 255;
  int tile = r255 >> 2, ocb = r255 & 3;  // ocb innermost: halo L2 reuse
  int ty = tile >> 3, tx = tile & 7;
  int oc0 = ocb * 64, oy0 = ty * 16, ox0 = tx * 16;
  int t = threadIdx.x;
  int w = t >> 6, l = t & 63, lh = l >> 4, col = l & 15;
  __shared__ short lds_in[3][1536 * 8];  // 3 x 24KB halo buffers
  int ocl = (w >> 1) * 32;
  int pyb = (w & 1) * 8;
  const char* xb = (const char*)(xT + ((size_t)b << 22));
  const char* gp[6];
  #pragma unroll
  for (int j = 0; j < 6; j++) {
    int i = t + (j << 8);
    int px = i >> 2, g = i & 3;
    int iy = px / 18, ix = px - iy * 18;
    int gy = oy0 - 1 + iy, gx = ox0 - 1 + ix;
    bool valid = (px < 324) && ((unsigned)gy < 128u) && ((unsigned)gx < 128u);
    gp[j] = valid ? xb + (((size_t)(gy << 7) + gx) << 9) + (g << 4) : zeropage;
  }

#define CSTAGE(dst, kc)                                                  \
  do {                                                                   \
    int koff = (kc) << 6;                                                \
    _Pragma("unroll") for (int j = 0; j < 6; j++) {                      \
      GLDS(gp[j] + koff, (dst) + (j * 256 + w * 64) * 8);                \
    }                                                                    \
  } while (0)

  // [kc][t9][oc][ic32]: wave base = (oc0+ocl+col)*32 + lh*8
  const short* wp = w2r + (size_t)(oc0 + ocl + col) * 32 + lh * 8;
  f32x4 acc[2][8] = {};
  bf16x8 Aa0[9], Aa1[9], Ab0[9], Ab1[9];
  CSTAGE(&lds_in[0][0], 0);
  CSTAGE(&lds_in[1][0], 1);
  #pragma unroll
  for (int t9 = 0; t9 < 9; t9++) {
    Aa0[t9] = *(const bf16x8*)(wp + t9 * 8192);
    Aa1[t9] = *(const bf16x8*)(wp + t9 * 8192 + 512);
  }
  asm volatile("s_waitcnt vmcnt(24)" ::: "memory");
  __builtin_amdgcn_s_barrier();
  __builtin_amdgcn_sched_barrier(0);

#define CONVSTEP(kc, Au0, Au1, Ap0, Ap1)                                   \
  do {                                                                     \
    short* cbuf = &lds_in[0][0] + ((kc) % 3) * 12288;                      \
    if ((kc) < 7) {                                                        \
      const short* wk = wp + ((kc) + 1) * 73728;                           \
      _Pragma("unroll") for (int t9 = 0; t9 < 9; t9++) {                   \
        Ap0[t9] = *(const bf16x8*)(wk + t9 * 8192);                        \
        Ap1[t9] = *(const bf16x8*)(wk + t9 * 8192 + 512);                  \
      }                                                                    \
    }                                                                      \
    if ((kc) < 6) CSTAGE(&lds_in[0][0] + (((kc) + 2) % 3) * 12288, (kc) + 2); \
    _Pragma("unroll") for (int rr = 0; rr < 10; rr++) {                    \
      bf16x8 fb[3];                                                        \
      _Pragma("unroll") for (int kw = 0; kw < 3; kw++)                     \
        fb[kw] = *(const bf16x8*)                                          \
            &cbuf[((pyb + rr) * 18 + col + kw) * 32 + lh * 8];             \
      _Pragma("unroll") for (int kw = 0; kw < 3; kw++) {                   \
        _Pragma("unroll") for (int kh = 0; kh < 3; kh++) {                 \
          int nf = rr - kh;                                                \
          if (nf >= 0 && nf < 8) {                                         \
            acc[0][nf] = MFMA16(Au0[kh * 3 + kw], fb[kw], acc[0][nf]);     \
            acc[1][nf] = MFMA16(Au1[kh * 3 + kw], fb[kw], acc[1][nf]);     \
          }                                                                \
        }                                                                  \
      }                                                                    \
    }                                                                      \
    if ((kc) < 6) {                                                        \
      asm volatile("s_waitcnt vmcnt(24)" ::: "memory");                    \
      __builtin_amdgcn_s_barrier();                                        \
      __builtin_amdgcn_sched_barrier(0);                                   \
    } else if ((kc) == 6) {                                                \
      asm volatile("s_waitcnt vmcnt(18)" ::: "memory");                    \
      __builtin_amdgcn_s_barrier();                                        \
      __builtin_amdgcn_sched_barrier(0);                                   \
    }                                                                      \
  } while (0)

  CONVSTEP(0, Aa0, Aa1, Ab0, Ab1);
  CONVSTEP(1, Ab0, Ab1, Aa0, Aa1);
  CONVSTEP(2, Aa0, Aa1, Ab0, Ab1);
  CONVSTEP(3, Ab0, Ab1, Aa0, Aa1);
  CONVSTEP(4, Aa0, Aa1, Ab0, Ab1);
  CONVSTEP(5, Ab0, Ab1, Aa0, Aa1);
  CONVSTEP(6, Aa0, Aa1, Ab0, Ab1);
  CONVSTEP(7, Ab0, Ab1, Aa0, Aa1);

  float* ob = out + ((size_t)b << 22);
  short* cb = c2b + ((size_t)b << 22);  // [n][c] layout when BF16OUT
  float s1[2][4] = {}, s2[2][4] = {};
  #pragma unroll
  for (int m = 0; m < 2; m++)
    #pragma unroll
    for (int nf = 0; nf < 8; nf++) {
      int oy = oy0 + pyb + nf;
      if (BF16OUT) {
        bf16x4 pv;
        #pragma unroll
        for (int r = 0; r < 4; r++) {
          float v = acc[m][nf][r];
          pv[r] = (short)f2bf(v);
          s1[m][r] += v;
          s2[m][r] += v * v;
        }
        int n = (oy << 7) + ox0 + col;
        int c = oc0 + ocl + m * 16 + lh * 4;
        *(bf16x4*)&cb[(size_t)n * 256 + c] = pv;
      } else {
        #pragma unroll
        for (int r = 0; r < 4; r++) {
          float v = acc[m][nf][r];
          int oc = oc0 + ocl + m * 16 + lh * 4 + r;
          ob[((size_t)oc << 14) + (oy << 7) + ox0 + col] = v;
          s1[m][r] += v;
          s2[m][r] += v * v;
        }
      }
    }
  #pragma unroll
  for (int m = 0; m < 2; m++)
    #pragma unroll
    for (int r = 0; r < 4; r++) {
      float a1v = s1[m][r], a2v = s2[m][r];
      a1v += __shfl_xor(a1v, 1, 64); a1v += __shfl_xor(a1v, 2, 64);
      a1v += __shfl_xor(a1v, 4, 64); a1v += __shfl_xor(a1v, 8, 64);
      a2v += __shfl_xor(a2v, 1, 64); a2v += __shfl_xor(a2v, 2, 64);
      a2v += __shfl_xor(a2v, 4, 64); a2v += __shfl_xor(a2v, 8, 64);
      if (col == 0) {
        int oc = oc0 + ocl + m * 16 + lh * 4 + r;
        atomicAdd(&bnsum[oc], a1v);
        atomicAdd(&bnsumsq[oc], a2v);
      }
    }
}

// ---------------- Mtb (bf16, swizzled) rows 0..255: Wv'@Pt + bv'*kssum
//                  rows 256..271: den tile (row 256 = kssum+eps, rest 0)
__global__ __launch_bounds__(256) void mt_kernel(
    const float* Wv, const float* bv, const float* Pt, const float* xsum,
    const float* kssum, short* Mtb, float* vsum) {
  int b = blockIdx.x >> 2, qg = blockIdx.x & 3;
  int c = threadIdx.x;
  const float* wrow = Wv + c * 256;
  const float* pb = Pt + ((size_t)b << 14);
  const float* xs = xsum + b * 256;
  float acc[16] = {};
  float vs = 0.f;
  for (int k = 0; k < 256; k++) {
    float wv = wrow[k];
    const float* pr = pb + k * 64 + qg * 16;
    #pragma unroll
    for (int j = 0; j < 16; j++) acc[j] = fmaf(wv, pr[j], acc[j]);
    if (qg == 0) vs = fmaf(wv, xs[k], vs);
  }
  float bvc = bv[c];
  char* mb = (char*)Mtb + (size_t)b * 34816;
  #pragma unroll
  for (int h = 0; h < 2; h++) {
    bf16x8 v;
    #pragma unroll
    for (int j = 0; j < 8; j++) {
      int q = qg * 16 + h * 8 + j;
      v[j] = (short)f2bf(acc[h * 8 + j] + bvc * kssum[b * 64 + q]);
    }
    int G = qg * 2 + h;
    *(bf16x8*)(mb + c * 128 + ((G ^ (c & 7)) << 4)) = v;
  }
  if (qg == 0) vsum[b * 256 + c] = vs + 16384.f * bvc;
  if (c < 16) {
    int row = 256 + c;
    #pragma unroll
    for (int h = 0; h < 2; h++) {
      bf16x8 v;
      #pragma unroll
      for (int j = 0; j < 8; j++)
        v[j] = (c == 0) ? (short)f2bf(kssum[b * 64 + qg * 16 + h * 8 + j] + 1e-6f)
                        : (short)0;
      int G = qg * 2 + h;
      *(bf16x8*)(mb + row * 128 + ((G ^ (row & 7)) << 4)) = v;
    }
  }
}

// ---------------- BN finalize
__global__ void bnfin_kernel(const float* bnsum, const float* bnsumsq,
                             const float* bn_w, const float* bn_b,
                             float* bnscale, float* bnshift) {
  int c = threadIdx.x;
  const float inv = 1.f / 131072.f;
  float mean = bnsum[c] * inv;
  float var = bnsumsq[c] * inv - mean * mean;
  float sc = bn_w[c] * rsqrtf(var + 1e-5f);
  bnscale[c] = sc;
  bnshift[c] = bn_b[c] - mean * sc;
}

// ---------------- final: out = gamma*tailor*(vsum + Qn^T@M) + BN(conv raw)
// MFMA: D[c][n] = Mtb[c][q] x QnT[n][q]; den via extra A-tile rows 256..271
// BF16C2=1: conv result read from c2b [n][c] bf16 (packed bf16x4 per m).
template <int BF16C2>
__global__ __launch_bounds__(256, 3) void final_kernel(
    const short* Mtb, const short* QnT, const short* c2b, const float* vsum,
    const float* bnscale, const float* bnshift, const float* gamma, float* out) {
  int b = blockIdx.x >> 7;
  int n0 = (blockIdx.x & 127) << 7;  // 128 n per block
  int t = threadIdx.x;
  int w = t >> 6, l = t & 63, lh = l >> 4, col = l & 15;
  __shared__ short mtb_lds[272 * 64];  // [row][64q], granule-swizzled
  __shared__ short qnt_lds[128 * 64];  // [n][64q], granule-swizzled
  const char* mb = (const char*)Mtb + (size_t)b * 34816;
  const char* qb = (const char*)QnT + (((size_t)b << 14) + n0) * 128;
  #pragma unroll
  for (int j = 0; j < 8; j++) {
    int i = t + (j << 8);
    GLDS(mb + i * 16, &mtb_lds[(j * 256 + w * 64) * 8]);
  }
  if (t < 128) {
    GLDS(mb + (t + 2048) * 16, &mtb_lds[(2048 + w * 64) * 8]);
  }
  #pragma unroll
  for (int j = 0; j < 4; j++) {
    int i = t + (j << 8);
    GLDS(qb + i * 16, &qnt_lds[(j * 256 + w * 64) * 8]);
  }
  float g = gamma[0];
  __syncthreads();
  #pragma unroll
  for (int nt = 0; nt < 2; nt++) {
    int nl = w * 32 + nt * 16 + col;  // local n row
    bf16x8 bfrag[2];
    #pragma unroll
    for (int kk = 0; kk < 2; kk++) {
      int gsl = (kk * 4 + lh) ^ (nl & 7);
      bfrag[kk] = *(const bf16x8*)&qnt_lds[nl * 64 + gsl * 8];
    }
    // den tile (A rows 256..271, row 256 = ks+eps); den for col n sits in
    // lane col (lh==0, reg 0) -> broadcast via shfl, no LDS round-trip
    f32x4 dacc = {};
    #pragma unroll
    for (int kk = 0; kk < 2; kk++) {
      int cr = 256 + col;
      int gsl = (kk * 4 + lh) ^ (cr & 7);
      bf16x8 afrag = *(const bf16x8*)&mtb_lds[cr * 64 + gsl * 8];
      dacc = MFMA16(afrag, bfrag[kk], dacc);
    }
    float den = __shfl(dacc[0], col, 64);
    float taiv = g / (16384.f + den);
    size_t base = ((size_t)b << 22) + n0 + w * 32 + nt * 16 + col;
    float* ob = out + base;
    // c2b [n][c]: row base for this thread's n
    const short* cb = c2b + ((size_t)b << 22) +
                      (size_t)(n0 + w * 32 + nt * 16 + col) * 256;
    const float* vsb = vsum + b * 256;
    #pragma unroll
    for (int m = 0; m < 16; m++) {
      f32x4 acc = {};
      #pragma unroll
      for (int kk = 0; kk < 2; kk++) {
        int cr = m * 16 + col;
        int gsl = (kk * 4 + lh) ^ (cr & 7);
        bf16x8 afrag = *(const bf16x8*)&mtb_lds[cr * 64 + gsl * 8];
        acc = MFMA16(afrag, bfrag[kk], acc);
      }
      int c0 = m * 16 + lh * 4;
      bf16x4 cv = {};
      if (BF16C2) cv = *(const bf16x4*)&cb[c0];
      f32x4 vsv = *(const f32x4*)&vsb[c0];
      f32x4 scv = *(const f32x4*)&bnscale[c0];
      f32x4 shv = *(const f32x4*)&bnshift[c0];
      #pragma unroll
      for (int r = 0; r < 4; r++) {
        float att = vsv[r] + acc[r];
        float c2 = BF16C2 ? bf2f((unsigned short)cv[r])
                          : ob[(size_t)(c0 + r) << 14];
        ob[(size_t)(c0 + r) << 14] = fmaf(taiv, att, fmaf(c2, scv[r], shv[r]));
      }
    }
  }
}

extern "C" void kernel_launch(void* const* d_in, const int* in_sizes, int n_in,
                              void* d_out, int out_size, void* d_ws, size_t ws_size,
                              hipStream_t stream) {
  const float* x = (const float*)d_in[0];
  const float* conv1_w = (const float*)d_in[1];
  const float* conv1_b = (const float*)d_in[2];
  const float* q_w = (const float*)d_in[3];
  const float* q_b = (const float*)d_in[4];
  const float* k_w = (const float*)d_in[5];
  const float* k_b = (const float*)d_in[6];
  const float* v_w = (const float*)d_in[7];
  const float* v_b = (const float*)d_in[8];
  const float* gamma = (const float*)d_in[9];
  const float* conv2_w = (const float*)d_in[10];
  // d_in[11] = conv2_b: unused, cancels exactly in train-mode BN
  const float* bn_w = (const float*)d_in[12];
  const float* bn_b = (const float*)d_in[13];

  char* ws = (char*)d_ws;
  char* zeropage = ws + 0;                   // 1024 (zeroed)
  float* kssum   = (float*)(ws + 1024);      // 8*64 (zeroed)
  float* bnsum   = (float*)(ws + 3072);      // 256 (zeroed)
  float* bnsumsq = (float*)(ws + 4096);      // 256 (zeroed)
  float* xsum    = (float*)(ws + 5120);      // 8*256 (zeroed)
  float* Pt      = (float*)(ws + 13312);     // 8*256*64 (zeroed)
  short* Wqk     = (short*)(ws + 537600);    // 128*256 bf16
  float* bqk     = (float*)(ws + 603136);    // 128
  float* Wv      = (float*)(ws + 603648);    // 256*256
  float* bv      = (float*)(ws + 865792);    // 256
  short* w2r     = (short*)(ws + 866816);    // [kc][t9][oc][ic32] bf16
  short* Mtb     = (short*)(ws + 2046464);   // 8*272*64 bf16 swizzled
  float* vsum    = (float*)(ws + 2324992);   // 8*256
  float* bnscale = (float*)(ws + 2333184);   // 256
  float* bnshift = (float*)(ws + 2334208);   // 256
  short* xT      = (short*)(ws + 2336768);   // 8*16384*256 bf16 (64 MB)
  short* QnT     = (short*)(ws + 69445632);  // 8*16384*64 bf16 swizzled
  short* Kn      = (short*)(ws + 86222848);  // 8*64*16384 bf16
  short* c2b     = (short*)(ws + 103000064); // 8*16384*256 bf16 [n][c] (64 MB)
  const size_t NEED_BF16 = 103000064ULL + 67108864ULL;  // 170,108,928

  float* out = (float*)d_out;
  bool use_bf16_c2 = (ws_size >= NEED_BF16);

  hipMemsetAsync(ws, 0, 537600, stream);  // zeropage..Pt
  compose_kernel<<<384, 256, 0, stream>>>(conv1_w, conv1_b, q_w, q_b, k_w, k_b,
                                          v_w, v_b, Wqk, bqk, Wv, bv);
  w2r_kernel<<<2304, 256, 0, stream>>>(conv2_w, w2r);
  xt_kernel<<<4096, 256, 0, stream>>>(x, xT, xsum);
  qk_kernel<<<1024, 256, 0, stream>>>(xT, Wqk, bqk, QnT, Kn, kssum);
  p_kernel<<<512, 256, 0, stream>>>(xT, Kn, Pt);
  if (use_bf16_c2)
    conv_kernel<1><<<2048, 256, 0, stream>>>(xT, w2r, out, c2b, bnsum, bnsumsq,
                                             zeropage);
  else
    conv_kernel<0><<<2048, 256, 0, stream>>>(xT, w2r, out, c2b, bnsum, bnsumsq,
                                             zeropage);
  mt_kernel<<<32, 256, 0, stream>>>(Wv, bv, Pt, xsum, kssum, Mtb, vsum);
  bnfin_kernel<<<1, 256, 0, stream>>>(bnsum, bnsumsq, bn_w, bn_b, bnscale, bnshift);
  if (use_bf16_c2)
    final_kernel<1><<<1024, 256, 0, stream>>>(Mtb, QnT, c2b, vsum, bnscale,
                                              bnshift, gamma, out);
  else
    final_kernel<0><<<1024, 256, 0, stream>>>(Mtb, QnT, c2b, vsum, bnscale,
                                              bnshift, gamma, out);
}